// Round 3
// baseline (9291.414 us; speedup 1.0000x reference)
//
#include <hip/hip_runtime.h>
#include <hip/hip_bf16.h>
#include <hip/hip_cooperative_groups.h>

#define BB 256
#define TT 128
#define NN 1024
#define HH 1024
#define G4 4096

namespace cg = cooperative_groups;

typedef __attribute__((ext_vector_type(4))) float f32x4;
typedef __attribute__((ext_vector_type(8))) short bf16x8;

__device__ __forceinline__ unsigned short f2bf(float f) {
    unsigned int u = __builtin_bit_cast(unsigned int, f);
    u += 0x7FFFu + ((u >> 16) & 1u);
    return (unsigned short)(u >> 16);
}
__device__ __forceinline__ float bf2f(unsigned short s) {
    unsigned int u = ((unsigned int)s) << 16;
    return __builtin_bit_cast(float, u);
}

// ---------------------------------------------------------------------------
// K1: attention weights (time-invariant) + input_weighted (f32) + w_in bf16
// ---------------------------------------------------------------------------
__global__ __launch_bounds__(512) void k_attn(
    const float* __restrict__ x, const float* __restrict__ attn_w,
    const float* __restrict__ attn_b, float* __restrict__ out0,
    unsigned short* __restrict__ win_bf)
{
    const int b = blockIdx.x;
    const int tid = threadIdx.x;
    const float* xb = x + (size_t)b * (TT * NN);
    const float* wx = attn_w + 2 * HH;

    float s0 = 0.f, s1 = 0.f;
    for (int t = 0; t < TT; ++t) {
        float2 v = *(const float2*)(xb + (size_t)t * NN + tid * 2);
        float w = wx[t];
        s0 += v.x * w; s1 += v.y * w;
    }
    float ab = attn_b[0];
    s0 += ab; s1 += ab;

    __shared__ float red[8];
    const int wv = tid >> 6, ln = tid & 63;
    float m = fmaxf(s0, s1);
#pragma unroll
    for (int off = 32; off > 0; off >>= 1) m = fmaxf(m, __shfl_xor(m, off));
    if (ln == 0) red[wv] = m;
    __syncthreads();
    m = red[0];
#pragma unroll
    for (int i = 1; i < 8; ++i) m = fmaxf(m, red[i]);

    float e0 = expf(s0 - m), e1 = expf(s1 - m);
    float sum = e0 + e1;
#pragma unroll
    for (int off = 32; off > 0; off >>= 1) sum += __shfl_xor(sum, off);
    __syncthreads();
    if (ln == 0) red[wv] = sum;
    __syncthreads();
    sum = 0.f;
#pragma unroll
    for (int i = 0; i < 8; ++i) sum += red[i];
    const float inv = 1.0f / sum;
    const float a0 = e0 * inv, a1 = e1 * inv;

    float* o = out0 + (size_t)b * (TT * NN);
    unsigned short* wb = win_bf + (size_t)b * (TT * NN);
    for (int t = 0; t < TT; ++t) {
        float2 v = *(const float2*)(xb + (size_t)t * NN + tid * 2);
        float2 w; w.x = a0 * v.x; w.y = a1 * v.y;
        *(float2*)(o + (size_t)t * NN + tid * 2) = w;
        unsigned int pk = (unsigned int)f2bf(w.x) | ((unsigned int)f2bf(w.y) << 16);
        *(unsigned int*)(wb + (size_t)t * NN + tid * 2) = pk;
    }
}

// ---------------------------------------------------------------------------
// K2: convert W_ih / W_hh to bf16 with gate-interleaved row perm p=j*4+g
// ---------------------------------------------------------------------------
__global__ __launch_bounds__(256) void k_prep_w(
    const float* __restrict__ Wih, const float* __restrict__ Whh,
    const float* __restrict__ bih, const float* __restrict__ bhh,
    unsigned short* __restrict__ WihP, unsigned short* __restrict__ WhhP,
    float* __restrict__ biasP)
{
    const int p = blockIdx.x;
    const int j = p >> 2, g = p & 3;
    const int r = g * HH + j;
    const int tid = threadIdx.x;
    {
        float4 v = *(const float4*)(Wih + (size_t)r * NN + tid * 4);
        ushort4 o;
        o.x = f2bf(v.x); o.y = f2bf(v.y); o.z = f2bf(v.z); o.w = f2bf(v.w);
        *(ushort4*)(WihP + (size_t)p * NN + tid * 4) = o;
    }
    {
        float4 v = *(const float4*)(Whh + (size_t)r * HH + tid * 4);
        ushort4 o;
        o.x = f2bf(v.x); o.y = f2bf(v.y); o.z = f2bf(v.z); o.w = f2bf(v.w);
        *(ushort4*)(WhhP + (size_t)p * HH + tid * 4) = o;
    }
    if (tid == 0) biasP[p] = bih[r] + bhh[r];
}

// ---------------------------------------------------------------------------
// K3: Xp = w_in_bf16 (32768,1024) @ WihP^T (4096,1024) -> bf16 (32768,4096)
// ---------------------------------------------------------------------------
__global__ __launch_bounds__(256) void k_gemm_xp(
    const unsigned short* __restrict__ A,
    const unsigned short* __restrict__ Bm,
    unsigned short* __restrict__ C)
{
    __shared__ unsigned short lA[128 * 32];
    __shared__ unsigned short lB[128 * 32];

    const int bid = blockIdx.x;
    const int cpx = gridDim.x >> 3;
    const int swz = (bid & 7) * cpx + (bid >> 3);
    const int NTN = G4 / 128;
    const int tm = swz / NTN, tn = swz % NTN;

    const int tid = threadIdx.x;
    const int wv = tid >> 6, ln = tid & 63;
    const int wr = wv >> 1, wc = wv & 1;

    f32x4 acc[4][4] = {};

    const unsigned short* Ag = A + (size_t)tm * 128 * NN;
    const unsigned short* Bg = Bm + (size_t)tn * 128 * NN;
    const int srow = ln >> 2;
    const int sseg = ln & 3;

    for (int k0 = 0; k0 < NN; k0 += 32) {
        __syncthreads();
#pragma unroll
        for (int q = 0; q < 2; ++q) {
            const int row = wv * 32 + q * 16 + srow;
            __builtin_amdgcn_global_load_lds(
                (const __attribute__((address_space(1))) void*)(Ag + (size_t)row * NN + k0 + sseg * 8),
                (__attribute__((address_space(3))) void*)(&lA[(wv * 32 + q * 16) * 32]),
                16, 0, 0);
            __builtin_amdgcn_global_load_lds(
                (const __attribute__((address_space(1))) void*)(Bg + (size_t)row * NN + k0 + sseg * 8),
                (__attribute__((address_space(3))) void*)(&lB[(wv * 32 + q * 16) * 32]),
                16, 0, 0);
        }
        __syncthreads();

        const int rlo = ln & 15, khi = ln >> 4;
        bf16x8 af[4], bfr[4];
#pragma unroll
        for (int m = 0; m < 4; ++m)
            af[m] = *(const bf16x8*)&lA[(wr * 64 + m * 16 + rlo) * 32 + khi * 8];
#pragma unroll
        for (int n = 0; n < 4; ++n)
            bfr[n] = *(const bf16x8*)&lB[(wc * 64 + n * 16 + rlo) * 32 + khi * 8];
#pragma unroll
        for (int m = 0; m < 4; ++m)
#pragma unroll
            for (int n = 0; n < 4; ++n)
                acc[m][n] = __builtin_amdgcn_mfma_f32_16x16x32_bf16(af[m], bfr[n], acc[m][n], 0, 0, 0);
    }

    const int rlo = ln & 15, rhi = ln >> 4;
#pragma unroll
    for (int m = 0; m < 4; ++m)
#pragma unroll
        for (int n = 0; n < 4; ++n)
#pragma unroll
            for (int j = 0; j < 4; ++j) {
                const int row = tm * 128 + wr * 64 + m * 16 + rhi * 4 + j;
                const int col = tn * 128 + wc * 64 + n * 16 + rlo;
                C[(size_t)row * G4 + col] = f2bf(acc[m][n][j]);
            }
}

// ---------------------------------------------------------------------------
// K4-persistent: whole recurrence in ONE cooperative kernel.
//   grid = 256 blocks (ti = bid>>6 batch tile of 64, tj = bid&63 -> 64 perm
//   cols = 16 hidden units). W_hh^perm slice LDS-resident (128 KiB, XOR-
//   swizzled), h double-buffered bf16 in global, c in registers, gate
//   transpose via CORRECT shfl_xor butterfly, Xp tile staged in LDS per step.
// ---------------------------------------------------------------------------
__global__ __launch_bounds__(256, 1) void k_recur(
    const unsigned short* __restrict__ WhhP,
    const unsigned short* __restrict__ Xp,
    const float* __restrict__ biasP,
    unsigned short* __restrict__ h0,
    unsigned short* __restrict__ h1,
    float* __restrict__ out1)
{
    __shared__ unsigned short lB[64 * 1024];   // 128 KiB  W_hh^perm slice
    __shared__ unsigned short lA[2][64 * 64];  //  16 KiB  h chunk dbuf
    __shared__ unsigned short lXp[64 * 64];    //   8 KiB  Xp tile

    cg::grid_group grid = cg::this_grid();

    const int bid = blockIdx.x;
    const int ti = bid >> 6, tj = bid & 63;
    const int tid = threadIdx.x;
    const int wv = tid >> 6, ln = tid & 63;
    const int wr = wv >> 1, wc = wv & 1;
    const int rlo = ln & 15, khi = ln >> 4;

    // ---- load W_hh slice once (pre-swizzled source -> linear LDS dest) ----
    {
        const char* base = (const char*)WhhP + (size_t)(tj * 64) * 2048;
#pragma unroll
        for (int q = 0; q < 32; ++q) {
            const int i = wv * 32 + q;
            const int r = i >> 1, half = i & 1;
            const int phys = half * 1024 + ln * 16;
            const int lb = phys ^ ((r & 7) << 4);
            __builtin_amdgcn_global_load_lds(
                (const __attribute__((address_space(1))) void*)(base + (size_t)r * 2048 + lb),
                (__attribute__((address_space(3))) void*)(&lB[r * 1024 + half * 512]),
                16, 0, 0);
        }
    }

    // per-lane bias (4 gates of my unit) for each n-frag
    float4 bias4[2];
#pragma unroll
    for (int n = 0; n < 2; ++n)
        bias4[n] = *(const float4*)&biasP[(tj * 16 + wc * 8 + n * 4 + ((ln & 15) >> 2)) * 4];

    float c_reg[2][2] = {{0.f, 0.f}, {0.f, 0.f}};

#define ISSUE_A(c_) do { \
    _Pragma("unroll") \
    for (int q_ = 0; q_ < 2; ++q_) { \
        const int i_ = wv * 2 + q_; \
        const int rr_ = 8 * i_ + (ln >> 3); \
        __builtin_amdgcn_global_load_lds( \
            (const __attribute__((address_space(1))) void*)(Abase + (size_t)rr_ * 2048 + (c_) * 128 + 16 * ((ln & 7) ^ (ln >> 3))), \
            (__attribute__((address_space(3))) void*)(&lA[(c_) & 1][i_ * 512]), \
            16, 0, 0); \
    } } while (0)

    for (int t = 0; t < TT; ++t) {
        const unsigned short* hR = (t & 1) ? h1 : h0;
        unsigned short* hW = (t & 1) ? h0 : h1;

        // stage Xp tile: rows = my 64 batches at step t, cols tj*64..+64
        {
#pragma unroll
            for (int q = 0; q < 2; ++q) {
                const int i = wv * 2 + q;
                const size_t bg = (size_t)(ti * 64 + 8 * i + (ln >> 3));
                __builtin_amdgcn_global_load_lds(
                    (const __attribute__((address_space(1))) void*)((const char*)Xp + ((bg * TT + t) << 13) + tj * 128 + (ln & 7) * 16),
                    (__attribute__((address_space(3))) void*)(&lXp[i * 512]),
                    16, 0, 0);
            }
        }

        f32x4 acc[2][2];
        {
            const f32x4 z = {0.f, 0.f, 0.f, 0.f};
            acc[0][0] = z; acc[0][1] = z; acc[1][0] = z; acc[1][1] = z;
        }

        if (t > 0) {
            const char* Abase = (const char*)hR + (size_t)(ti * 64) * 2048;
            ISSUE_A(0);
            ISSUE_A(1);
#pragma unroll
            for (int c = 0; c < 16; ++c) {
                if (c < 15) { asm volatile("s_waitcnt vmcnt(2)" ::: "memory"); }
                else        { asm volatile("s_waitcnt vmcnt(0)" ::: "memory"); }
                __builtin_amdgcn_s_barrier();              // chunk c resident

                bf16x8 af[2][2], bfr[2][2];
#pragma unroll
                for (int kk = 0; kk < 2; ++kk)
#pragma unroll
                    for (int m = 0; m < 2; ++m) {
                        const int row = wr * 32 + m * 16 + rlo;
                        const int off = (kk * 64 + khi * 16) ^ ((row & 7) << 4);
                        af[kk][m] = *(const bf16x8*)((const char*)lA[c & 1] + row * 128 + off);
                    }
#pragma unroll
                for (int kk = 0; kk < 2; ++kk)
#pragma unroll
                    for (int n = 0; n < 2; ++n) {
                        const int row = wc * 32 + n * 16 + rlo;
                        const int off = (c * 128 + kk * 64 + khi * 16) ^ ((row & 7) << 4);
                        bfr[kk][n] = *(const bf16x8*)((const char*)lB + row * 2048 + off);
                    }
                asm volatile("s_waitcnt lgkmcnt(0)" ::: "memory");
                __builtin_amdgcn_sched_barrier(0);
                __builtin_amdgcn_s_barrier();              // all reads of buf done
                if (c < 14) ISSUE_A(c + 2);
#pragma unroll
                for (int kk = 0; kk < 2; ++kk)
#pragma unroll
                    for (int m = 0; m < 2; ++m)
#pragma unroll
                        for (int n = 0; n < 2; ++n)
                            acc[m][n] = __builtin_amdgcn_mfma_f32_16x16x32_bf16(af[kk][m], bfr[kk][n], acc[m][n], 0, 0, 0);
            }
        } else {
            asm volatile("s_waitcnt vmcnt(0)" ::: "memory");
            __builtin_amdgcn_s_barrier();                  // Xp (+W_hh) resident
        }

        // ---- gate transpose: correct 4x4 butterfly over 4-lane groups ----
#pragma unroll
        for (int m = 0; m < 2; ++m)
#pragma unroll
            for (int n = 0; n < 2; ++n) {
                f32x4 v = acc[m][n], u, w;
#pragma unroll
                for (int k = 0; k < 4; ++k) {
                    float s = __shfl_xor(v[k ^ 1], 1);
                    u[k] = ((k & 1) == (ln & 1)) ? v[k] : s;
                }
#pragma unroll
                for (int k = 0; k < 4; ++k) {
                    float s = __shfl_xor(u[k ^ 2], 2);
                    w[k] = (((k >> 1) & 1) == ((ln >> 1) & 1)) ? u[k] : s;
                }
                const int r_loc = wr * 32 + m * 16 + ((ln >> 4) << 2) + (ln & 3);
                const int u_loc = wc * 8 + n * 4 + ((ln & 15) >> 2);
                const ushort4 xp4 = *(const ushort4*)((const char*)lXp + r_loc * 128 + u_loc * 8);
                const float gi = w[0] + bf2f(xp4.x) + bias4[n].x;
                const float gf = w[1] + bf2f(xp4.y) + bias4[n].y;
                const float gg = w[2] + bf2f(xp4.z) + bias4[n].z;
                const float go = w[3] + bf2f(xp4.w) + bias4[n].w;
                const float i_ = 1.f / (1.f + expf(-gi));
                const float f_ = 1.f / (1.f + expf(-gf));
                const float g_ = tanhf(gg);
                const float o_ = 1.f / (1.f + expf(-go));
                const float cc = f_ * c_reg[m][n] + i_ * g_;
                c_reg[m][n] = cc;
                const float h_ = o_ * tanhf(cc);
                const int bg = ti * 64 + r_loc;
                const int ug = tj * 16 + u_loc;
                out1[(size_t)bg * (TT * HH) + (size_t)t * HH + ug] = h_;
                hW[(size_t)bg * HH + ug] = f2bf(h_);
            }

        if (t < TT - 1) {
            __threadfence();
            grid.sync();
        }
    }
#undef ISSUE_A
}

// ---------------------------------------------------------------------------
// Fallback per-step kernel (used only if cooperative launch is unavailable)
// ---------------------------------------------------------------------------
__global__ __launch_bounds__(256) void k_step(
    const int t,
    const unsigned short* __restrict__ hbf,
    const unsigned short* __restrict__ WhhP,
    const unsigned short* __restrict__ Xp,
    const float* __restrict__ biasP,
    float* __restrict__ cbuf,
    unsigned short* __restrict__ hbf_out,
    float* __restrict__ out1)
{
    __shared__ unsigned short lA[64 * 32];
    __shared__ unsigned short lB[64 * 32];
    __shared__ float gsm[64][65];

    const int bid = blockIdx.x;
    const int ti = bid >> 6;
    const int tj = bid & 63;
    const int tid = threadIdx.x;
    const int wv = tid >> 6, ln = tid & 63;
    const int wr = wv >> 1, wc = wv & 1;

    f32x4 acc[2][2] = {};

    const unsigned short* Ag = hbf + (size_t)ti * 64 * HH;
    const unsigned short* Bg = WhhP + (size_t)tj * 64 * HH;
    const int srow = ln >> 2, sseg = ln & 3;

    for (int k0 = 0; k0 < HH; k0 += 32) {
        __syncthreads();
        {
            const int row = wv * 16 + srow;
            __builtin_amdgcn_global_load_lds(
                (const __attribute__((address_space(1))) void*)(Ag + (size_t)row * HH + k0 + sseg * 8),
                (__attribute__((address_space(3))) void*)(&lA[(wv * 16) * 32]),
                16, 0, 0);
            __builtin_amdgcn_global_load_lds(
                (const __attribute__((address_space(1))) void*)(Bg + (size_t)row * HH + k0 + sseg * 8),
                (__attribute__((address_space(3))) void*)(&lB[(wv * 16) * 32]),
                16, 0, 0);
        }
        __syncthreads();

        const int rlo = ln & 15, khi = ln >> 4;
        bf16x8 af[2], bfr[2];
#pragma unroll
        for (int m = 0; m < 2; ++m)
            af[m] = *(const bf16x8*)&lA[(wr * 32 + m * 16 + rlo) * 32 + khi * 8];
#pragma unroll
        for (int n = 0; n < 2; ++n)
            bfr[n] = *(const bf16x8*)&lB[(wc * 32 + n * 16 + rlo) * 32 + khi * 8];
#pragma unroll
        for (int m = 0; m < 2; ++m)
#pragma unroll
            for (int n = 0; n < 2; ++n)
                acc[m][n] = __builtin_amdgcn_mfma_f32_16x16x32_bf16(af[m], bfr[n], acc[m][n], 0, 0, 0);
    }

    {
        const int rlo = ln & 15, rhi = ln >> 4;
#pragma unroll
        for (int m = 0; m < 2; ++m)
#pragma unroll
            for (int n = 0; n < 2; ++n)
#pragma unroll
                for (int j = 0; j < 4; ++j)
                    gsm[wr * 32 + m * 16 + rhi * 4 + j][wc * 32 + n * 16 + rlo] = acc[m][n][j];
    }
    __syncthreads();

    const int jl = tid & 15;
    const int bq = tid >> 4;
    const float4 bias4 = *(const float4*)&biasP[tj * 64 + jl * 4];
#pragma unroll
    for (int q = 0; q < 4; ++q) {
        const int bl = q * 16 + bq;
        const int bg = ti * 64 + bl;
        const int jg = tj * 16 + jl;
        ushort4 xp4 = *(const ushort4*)&Xp[((size_t)bg * TT + t) * G4 + tj * 64 + jl * 4];
        float gi = gsm[bl][jl * 4 + 0] + bf2f(xp4.x) + bias4.x;
        float gf = gsm[bl][jl * 4 + 1] + bf2f(xp4.y) + bias4.y;
        float gg = gsm[bl][jl * 4 + 2] + bf2f(xp4.z) + bias4.z;
        float go = gsm[bl][jl * 4 + 3] + bf2f(xp4.w) + bias4.w;
        float i_ = 1.f / (1.f + expf(-gi));
        float f_ = 1.f / (1.f + expf(-gf));
        float g_ = tanhf(gg);
        float o_ = 1.f / (1.f + expf(-go));
        float c_ = f_ * cbuf[(size_t)bg * HH + jg] + i_ * g_;
        cbuf[(size_t)bg * HH + jg] = c_;
        float h_ = o_ * tanhf(c_);
        out1[(size_t)bg * (TT * HH) + (size_t)t * HH + jg] = h_;
        hbf_out[(size_t)bg * HH + jg] = f2bf(h_);
    }
}

__global__ __launch_bounds__(256) void k_zero(float4* __restrict__ p)
{
    p[blockIdx.x * 256 + threadIdx.x] = make_float4(0.f, 0.f, 0.f, 0.f);
}

extern "C" void kernel_launch(void* const* d_in, const int* in_sizes, int n_in,
                              void* d_out, int out_size, void* d_ws, size_t ws_size,
                              hipStream_t stream)
{
    const float* x      = (const float*)d_in[0];
    const float* Wih    = (const float*)d_in[1];
    const float* Whh    = (const float*)d_in[2];
    const float* bih    = (const float*)d_in[3];
    const float* bhh    = (const float*)d_in[4];
    const float* attn_w = (const float*)d_in[5];
    const float* attn_b = (const float*)d_in[6];

    float* out0 = (float*)d_out;                               // (B,T,N)
    float* out1 = (float*)d_out + (size_t)BB * TT * NN;        // (B,T,H)

    char* w = (char*)d_ws;
    unsigned short* WihP  = (unsigned short*)(w);                       //  8 MiB
    unsigned short* WhhP  = (unsigned short*)(w + 8388608);             //  8 MiB
    float*          biasP = (float*)(w + 16777216);                     // 16 KiB
    unsigned short* winbf = (unsigned short*)(w + 16793600);            // 64 MiB
    unsigned short* Xp    = (unsigned short*)(w + 83902464);            // 256 MiB
    unsigned short* hbf0  = (unsigned short*)(w + 352337920);           // 512 KiB
    unsigned short* hbf1  = (unsigned short*)(w + 352862208);           // 512 KiB
    float*          cbuf  = (float*)(w + 353386496);                    //   1 MiB

    k_attn<<<BB, 512, 0, stream>>>(x, attn_w, attn_b, out0, winbf);
    k_prep_w<<<G4, 256, 0, stream>>>(Wih, Whh, bih, bhh, WihP, WhhP, biasP);
    k_gemm_xp<<<(BB * TT / 128) * (G4 / 128), 256, 0, stream>>>(winbf, WihP, Xp);

    // persistent cooperative recurrence
    {
        const unsigned short* WhhP_c = WhhP;
        const unsigned short* Xp_c = Xp;
        const float* biasP_c = biasP;
        unsigned short* h0_c = hbf0;
        unsigned short* h1_c = hbf1;
        float* out1_c = out1;
        void* args[] = { (void*)&WhhP_c, (void*)&Xp_c, (void*)&biasP_c,
                         (void*)&h0_c, (void*)&h1_c, (void*)&out1_c };
        hipError_t err = hipLaunchCooperativeKernel((void*)k_recur, dim3(256), dim3(256),
                                                    args, 0, stream);
        if (err != hipSuccess) {
            // fallback: per-step launches (old path)
            k_zero<<<512, 256, 0, stream>>>((float4*)hbf0);
            for (int t = 0; t < TT; ++t) {
                const unsigned short* hin = (t & 1) ? hbf1 : hbf0;
                unsigned short* hout      = (t & 1) ? hbf0 : hbf1;
                k_step<<<256, 256, 0, stream>>>(t, hin, WhhP, Xp, biasP, cbuf, hout, out1);
            }
        }
    }
}

// Round 4
// 1921.887 us; speedup vs baseline: 4.8345x; 4.8345x over previous
//
#include <hip/hip_runtime.h>
#include <hip/hip_bf16.h>

#define BB 256
#define TT 128
#define NN 1024
#define HH 1024
#define G4 4096

typedef __attribute__((ext_vector_type(4))) float f32x4;
typedef __attribute__((ext_vector_type(8))) short bf16x8;

__device__ __forceinline__ unsigned short f2bf(float f) {
    unsigned int u = __builtin_bit_cast(unsigned int, f);
    u += 0x7FFFu + ((u >> 16) & 1u);
    return (unsigned short)(u >> 16);
}
__device__ __forceinline__ float bf2f(unsigned short s) {
    unsigned int u = ((unsigned int)s) << 16;
    return __builtin_bit_cast(float, u);
}

// ---------------------------------------------------------------------------
// K1: attention weights (time-invariant) + input_weighted (f32) + w_in bf16
// ---------------------------------------------------------------------------
__global__ __launch_bounds__(512) void k_attn(
    const float* __restrict__ x, const float* __restrict__ attn_w,
    const float* __restrict__ attn_b, float* __restrict__ out0,
    unsigned short* __restrict__ win_bf)
{
    const int b = blockIdx.x;
    const int tid = threadIdx.x;
    const float* xb = x + (size_t)b * (TT * NN);
    const float* wx = attn_w + 2 * HH;

    float s0 = 0.f, s1 = 0.f;
    for (int t = 0; t < TT; ++t) {
        float2 v = *(const float2*)(xb + (size_t)t * NN + tid * 2);
        float w = wx[t];
        s0 += v.x * w; s1 += v.y * w;
    }
    float ab = attn_b[0];
    s0 += ab; s1 += ab;

    __shared__ float red[8];
    const int wv = tid >> 6, ln = tid & 63;
    float m = fmaxf(s0, s1);
#pragma unroll
    for (int off = 32; off > 0; off >>= 1) m = fmaxf(m, __shfl_xor(m, off));
    if (ln == 0) red[wv] = m;
    __syncthreads();
    m = red[0];
#pragma unroll
    for (int i = 1; i < 8; ++i) m = fmaxf(m, red[i]);

    float e0 = expf(s0 - m), e1 = expf(s1 - m);
    float sum = e0 + e1;
#pragma unroll
    for (int off = 32; off > 0; off >>= 1) sum += __shfl_xor(sum, off);
    __syncthreads();
    if (ln == 0) red[wv] = sum;
    __syncthreads();
    sum = 0.f;
#pragma unroll
    for (int i = 0; i < 8; ++i) sum += red[i];
    const float inv = 1.0f / sum;
    const float a0 = e0 * inv, a1 = e1 * inv;

    float* o = out0 + (size_t)b * (TT * NN);
    unsigned short* wb = win_bf + (size_t)b * (TT * NN);
    for (int t = 0; t < TT; ++t) {
        float2 v = *(const float2*)(xb + (size_t)t * NN + tid * 2);
        float2 w; w.x = a0 * v.x; w.y = a1 * v.y;
        *(float2*)(o + (size_t)t * NN + tid * 2) = w;
        unsigned int pk = (unsigned int)f2bf(w.x) | ((unsigned int)f2bf(w.y) << 16);
        *(unsigned int*)(wb + (size_t)t * NN + tid * 2) = pk;
    }
}

// ---------------------------------------------------------------------------
// K2: convert W_ih / W_hh to bf16 with gate-interleaved row perm p=j*4+g
// ---------------------------------------------------------------------------
__global__ __launch_bounds__(256) void k_prep_w(
    const float* __restrict__ Wih, const float* __restrict__ Whh,
    const float* __restrict__ bih, const float* __restrict__ bhh,
    unsigned short* __restrict__ WihP, unsigned short* __restrict__ WhhP,
    float* __restrict__ biasP)
{
    const int p = blockIdx.x;
    const int j = p >> 2, g = p & 3;
    const int r = g * HH + j;
    const int tid = threadIdx.x;
    {
        float4 v = *(const float4*)(Wih + (size_t)r * NN + tid * 4);
        ushort4 o;
        o.x = f2bf(v.x); o.y = f2bf(v.y); o.z = f2bf(v.z); o.w = f2bf(v.w);
        *(ushort4*)(WihP + (size_t)p * NN + tid * 4) = o;
    }
    {
        float4 v = *(const float4*)(Whh + (size_t)r * HH + tid * 4);
        ushort4 o;
        o.x = f2bf(v.x); o.y = f2bf(v.y); o.z = f2bf(v.z); o.w = f2bf(v.w);
        *(ushort4*)(WhhP + (size_t)p * HH + tid * 4) = o;
    }
    if (tid == 0) biasP[p] = bih[r] + bhh[r];
}

// ---------------------------------------------------------------------------
// K3: Xp = w_in_bf16 (32768,1024) @ WihP^T (4096,1024) -> bf16 (32768,4096)
// ---------------------------------------------------------------------------
__global__ __launch_bounds__(256) void k_gemm_xp(
    const unsigned short* __restrict__ A,
    const unsigned short* __restrict__ Bm,
    unsigned short* __restrict__ C)
{
    __shared__ unsigned short lA[128 * 32];
    __shared__ unsigned short lB[128 * 32];

    const int bid = blockIdx.x;
    const int cpx = gridDim.x >> 3;
    const int swz = (bid & 7) * cpx + (bid >> 3);
    const int NTN = G4 / 128;
    const int tm = swz / NTN, tn = swz % NTN;

    const int tid = threadIdx.x;
    const int wv = tid >> 6, ln = tid & 63;
    const int wr = wv >> 1, wc = wv & 1;

    f32x4 acc[4][4] = {};

    const unsigned short* Ag = A + (size_t)tm * 128 * NN;
    const unsigned short* Bg = Bm + (size_t)tn * 128 * NN;
    const int srow = ln >> 2;
    const int sseg = ln & 3;

    for (int k0 = 0; k0 < NN; k0 += 32) {
        __syncthreads();
#pragma unroll
        for (int q = 0; q < 2; ++q) {
            const int row = wv * 32 + q * 16 + srow;
            __builtin_amdgcn_global_load_lds(
                (const __attribute__((address_space(1))) void*)(Ag + (size_t)row * NN + k0 + sseg * 8),
                (__attribute__((address_space(3))) void*)(&lA[(wv * 32 + q * 16) * 32]),
                16, 0, 0);
            __builtin_amdgcn_global_load_lds(
                (const __attribute__((address_space(1))) void*)(Bg + (size_t)row * NN + k0 + sseg * 8),
                (__attribute__((address_space(3))) void*)(&lB[(wv * 32 + q * 16) * 32]),
                16, 0, 0);
        }
        __syncthreads();

        const int rlo = ln & 15, khi = ln >> 4;
        bf16x8 af[4], bfr[4];
#pragma unroll
        for (int m = 0; m < 4; ++m)
            af[m] = *(const bf16x8*)&lA[(wr * 64 + m * 16 + rlo) * 32 + khi * 8];
#pragma unroll
        for (int n = 0; n < 4; ++n)
            bfr[n] = *(const bf16x8*)&lB[(wc * 64 + n * 16 + rlo) * 32 + khi * 8];
#pragma unroll
        for (int m = 0; m < 4; ++m)
#pragma unroll
            for (int n = 0; n < 4; ++n)
                acc[m][n] = __builtin_amdgcn_mfma_f32_16x16x32_bf16(af[m], bfr[n], acc[m][n], 0, 0, 0);
    }

    const int rlo = ln & 15, rhi = ln >> 4;
#pragma unroll
    for (int m = 0; m < 4; ++m)
#pragma unroll
        for (int n = 0; n < 4; ++n)
#pragma unroll
            for (int j = 0; j < 4; ++j) {
                const int row = tm * 128 + wr * 64 + m * 16 + rhi * 4 + j;
                const int col = tn * 128 + wc * 64 + n * 16 + rlo;
                C[(size_t)row * G4 + col] = f2bf(acc[m][n][j]);
            }
}

// ---------------------------------------------------------------------------
// K4 v2 (per step): G' = h@WhhP^T + Xp + bias -> LSTM update.
//   64 batch x 64 perm-cols per block, 256 blocks, 4 waves (32x32 each).
//   BK=128, 3-deep LDS rotation, counted vmcnt (T3+T4), XOR-swizzled LDS
//   via pre-swizzled global_load_lds sources; register-butterfly epilogue.
// ---------------------------------------------------------------------------
__global__ __launch_bounds__(256) void k_step2(
    const int t,
    const unsigned short* __restrict__ hbf,
    const unsigned short* __restrict__ WhhP,
    const unsigned short* __restrict__ Xp,
    const float* __restrict__ biasP,
    float* __restrict__ cbuf,
    unsigned short* __restrict__ hbf_out,
    float* __restrict__ out1)
{
    __shared__ unsigned short lA[3][64 * 128];   // 3 x 16 KiB
    __shared__ unsigned short lB[3][64 * 128];   // 3 x 16 KiB
    __shared__ unsigned short lXp[64 * 64];      // 8 KiB

    const int bid = blockIdx.x;
    const int ti = bid >> 6, tj = bid & 63;
    const int tid = threadIdx.x;
    const int wv = tid >> 6, ln = tid & 63;
    const int wr = wv >> 1, wc = wv & 1;
    const int rlo = ln & 15, khi = ln >> 4;

    // ---- stage Xp tile (oldest in vmcnt queue) ----
#pragma unroll
    for (int q = 0; q < 2; ++q) {
        const int i = wv * 2 + q;
        const size_t bg = (size_t)(ti * 64 + 8 * i + (ln >> 3));
        __builtin_amdgcn_global_load_lds(
            (const __attribute__((address_space(1))) void*)((const char*)Xp + ((bg * TT + t) << 13) + tj * 128 + (ln & 7) * 16),
            (__attribute__((address_space(3))) void*)(&lXp[i * 512]),
            16, 0, 0);
    }

    const char* Ab = (const char*)hbf + (size_t)(ti * 64) * 2048;
    const char* Bb = (const char*)WhhP + (size_t)(tj * 64) * 2048;
    const int sr = ln >> 4;      // row within 4-row group
    const int ss = ln & 15;      // 16B segment

    // 8 global_load_lds per wave per stage (4 A + 4 B)
#define STAGE(buf_, c_) do { \
    _Pragma("unroll") \
    for (int q_ = 0; q_ < 4; ++q_) { \
        const int ia_ = wv * 4 + q_; \
        const int r_ = ia_ * 4 + sr; \
        const int so_ = ((ss ^ (r_ & 7)) << 4); \
        __builtin_amdgcn_global_load_lds( \
            (const __attribute__((address_space(1))) void*)(Ab + (size_t)r_ * 2048 + (c_) * 256 + so_), \
            (__attribute__((address_space(3))) void*)((char*)&lA[buf_][0] + ia_ * 1024), \
            16, 0, 0); \
        __builtin_amdgcn_global_load_lds( \
            (const __attribute__((address_space(1))) void*)(Bb + (size_t)r_ * 2048 + (c_) * 256 + so_), \
            (__attribute__((address_space(3))) void*)((char*)&lB[buf_][0] + ia_ * 1024), \
            16, 0, 0); \
    } } while (0)

    STAGE(0, 0);
    STAGE(1, 1);
    STAGE(2, 2);

    float4 bias4[2];
#pragma unroll
    for (int n = 0; n < 2; ++n)
        bias4[n] = *(const float4*)&biasP[(tj * 16 + wc * 8 + n * 4 + ((ln & 15) >> 2)) * 4];

    f32x4 acc[2][2] = {};

#pragma unroll
    for (int c = 0; c < 8; ++c) {
        const int buf = c % 3;
        if (c < 6)       { asm volatile("s_waitcnt vmcnt(16)" ::: "memory"); }
        else if (c == 6) { asm volatile("s_waitcnt vmcnt(8)"  ::: "memory"); }
        else             { asm volatile("s_waitcnt vmcnt(0)"  ::: "memory"); }
        __builtin_amdgcn_s_barrier();          // stage c resident

        bf16x8 af[4][2], bfr[4][2];
#pragma unroll
        for (int kk = 0; kk < 4; ++kk) {
#pragma unroll
            for (int m = 0; m < 2; ++m) {
                const int row = wr * 32 + m * 16 + rlo;
                const int off = (kk * 64 + khi * 16) ^ ((row & 7) << 4);
                af[kk][m] = *(const bf16x8*)((const char*)&lA[buf][0] + row * 256 + off);
            }
#pragma unroll
            for (int n = 0; n < 2; ++n) {
                const int row = wc * 32 + n * 16 + rlo;
                const int off = (kk * 64 + khi * 16) ^ ((row & 7) << 4);
                bfr[kk][n] = *(const bf16x8*)((const char*)&lB[buf][0] + row * 256 + off);
            }
        }
        asm volatile("s_waitcnt lgkmcnt(0)" ::: "memory");
        __builtin_amdgcn_sched_barrier(0);
        __builtin_amdgcn_s_barrier();          // reads of buf done
        if (c < 5) STAGE((c + 3) % 3, c + 3);  // refill this buffer
#pragma unroll
        for (int kk = 0; kk < 4; ++kk)
#pragma unroll
            for (int m = 0; m < 2; ++m)
#pragma unroll
                for (int n = 0; n < 2; ++n)
                    acc[m][n] = __builtin_amdgcn_mfma_f32_16x16x32_bf16(af[kk][m], bfr[kk][n], acc[m][n], 0, 0, 0);
    }
#undef STAGE

    // ---- gate transpose (verified butterfly) + LSTM pointwise ----
#pragma unroll
    for (int m = 0; m < 2; ++m)
#pragma unroll
        for (int n = 0; n < 2; ++n) {
            f32x4 v = acc[m][n], u, w;
#pragma unroll
            for (int k = 0; k < 4; ++k) {
                float s = __shfl_xor(v[k ^ 1], 1);
                u[k] = ((k & 1) == (ln & 1)) ? v[k] : s;
            }
#pragma unroll
            for (int k = 0; k < 4; ++k) {
                float s = __shfl_xor(u[k ^ 2], 2);
                w[k] = (((k >> 1) & 1) == ((ln >> 1) & 1)) ? u[k] : s;
            }
            const int r_loc = wr * 32 + m * 16 + ((ln >> 4) << 2) + (ln & 3);
            const int u_loc = wc * 8 + n * 4 + ((ln & 15) >> 2);
            const ushort4 xp4 = *(const ushort4*)((const char*)lXp + r_loc * 128 + u_loc * 8);
            const float gi = w[0] + bf2f(xp4.x) + bias4[n].x;
            const float gf = w[1] + bf2f(xp4.y) + bias4[n].y;
            const float gg = w[2] + bf2f(xp4.z) + bias4[n].z;
            const float go = w[3] + bf2f(xp4.w) + bias4[n].w;
            const float i_ = 1.f / (1.f + expf(-gi));
            const float f_ = 1.f / (1.f + expf(-gf));
            const float g_ = tanhf(gg);
            const float o_ = 1.f / (1.f + expf(-go));
            const int bg = ti * 64 + r_loc;
            const int ug = tj * 16 + u_loc;
            const float cprev = cbuf[(size_t)bg * HH + ug];
            const float cc = f_ * cprev + i_ * g_;
            cbuf[(size_t)bg * HH + ug] = cc;
            const float h_ = o_ * tanhf(cc);
            out1[(size_t)bg * (TT * HH) + (size_t)t * HH + ug] = h_;
            hbf_out[(size_t)bg * HH + ug] = f2bf(h_);
        }
}

// zero-init: clears hbf0|hbf1|cbuf (2 MiB contiguous)
__global__ __launch_bounds__(256) void k_zero(float4* __restrict__ p)
{
    p[blockIdx.x * 256 + threadIdx.x] = make_float4(0.f, 0.f, 0.f, 0.f);
}

extern "C" void kernel_launch(void* const* d_in, const int* in_sizes, int n_in,
                              void* d_out, int out_size, void* d_ws, size_t ws_size,
                              hipStream_t stream)
{
    const float* x      = (const float*)d_in[0];
    const float* Wih    = (const float*)d_in[1];
    const float* Whh    = (const float*)d_in[2];
    const float* bih    = (const float*)d_in[3];
    const float* bhh    = (const float*)d_in[4];
    const float* attn_w = (const float*)d_in[5];
    const float* attn_b = (const float*)d_in[6];

    float* out0 = (float*)d_out;                               // (B,T,N)
    float* out1 = (float*)d_out + (size_t)BB * TT * NN;        // (B,T,H)

    char* w = (char*)d_ws;
    unsigned short* WihP  = (unsigned short*)(w);                       //  8 MiB
    unsigned short* WhhP  = (unsigned short*)(w + 8388608);             //  8 MiB
    float*          biasP = (float*)(w + 16777216);                     // 16 KiB
    unsigned short* winbf = (unsigned short*)(w + 16793600);            // 64 MiB
    unsigned short* Xp    = (unsigned short*)(w + 83902464);            // 256 MiB
    unsigned short* hbf0  = (unsigned short*)(w + 352337920);           // 512 KiB
    unsigned short* hbf1  = (unsigned short*)(w + 352862208);           // 512 KiB
    float*          cbuf  = (float*)(w + 353386496);                    //   1 MiB

    k_attn<<<BB, 512, 0, stream>>>(x, attn_w, attn_b, out0, winbf);
    k_prep_w<<<G4, 256, 0, stream>>>(Wih, Whh, bih, bhh, WihP, WhhP, biasP);
    k_gemm_xp<<<(BB * TT / 128) * (G4 / 128), 256, 0, stream>>>(winbf, WihP, Xp);
    k_zero<<<512, 256, 0, stream>>>((float4*)hbf0);   // h(t=0)=0, c=0

    for (int t = 0; t < TT; ++t) {
        const unsigned short* hin = (t & 1) ? hbf1 : hbf0;
        unsigned short* hout      = (t & 1) ? hbf0 : hbf1;
        k_step2<<<256, 256, 0, stream>>>(t, hin, WhhP, Xp, biasP, cbuf, hout, out1);
    }
}

// Round 5
// 1717.424 us; speedup vs baseline: 5.4101x; 1.1191x over previous
//
#include <hip/hip_runtime.h>
#include <hip/hip_bf16.h>

#define BB 256
#define TT 128
#define NN 1024
#define HH 1024
#define G4 4096

typedef __attribute__((ext_vector_type(4))) float f32x4;
typedef __attribute__((ext_vector_type(8))) short bf16x8;

__device__ __forceinline__ unsigned short f2bf(float f) {
    unsigned int u = __builtin_bit_cast(unsigned int, f);
    u += 0x7FFFu + ((u >> 16) & 1u);
    return (unsigned short)(u >> 16);
}
__device__ __forceinline__ float bf2f(unsigned short s) {
    unsigned int u = ((unsigned int)s) << 16;
    return __builtin_bit_cast(float, u);
}

// ---------------------------------------------------------------------------
// K1: attention weights (time-invariant) + input_weighted (f32) + w_in bf16
// ---------------------------------------------------------------------------
__global__ __launch_bounds__(512) void k_attn(
    const float* __restrict__ x, const float* __restrict__ attn_w,
    const float* __restrict__ attn_b, float* __restrict__ out0,
    unsigned short* __restrict__ win_bf)
{
    const int b = blockIdx.x;
    const int tid = threadIdx.x;
    const float* xb = x + (size_t)b * (TT * NN);
    const float* wx = attn_w + 2 * HH;

    float s0 = 0.f, s1 = 0.f;
    for (int t = 0; t < TT; ++t) {
        float2 v = *(const float2*)(xb + (size_t)t * NN + tid * 2);
        float w = wx[t];
        s0 += v.x * w; s1 += v.y * w;
    }
    float ab = attn_b[0];
    s0 += ab; s1 += ab;

    __shared__ float red[8];
    const int wv = tid >> 6, ln = tid & 63;
    float m = fmaxf(s0, s1);
#pragma unroll
    for (int off = 32; off > 0; off >>= 1) m = fmaxf(m, __shfl_xor(m, off));
    if (ln == 0) red[wv] = m;
    __syncthreads();
    m = red[0];
#pragma unroll
    for (int i = 1; i < 8; ++i) m = fmaxf(m, red[i]);

    float e0 = expf(s0 - m), e1 = expf(s1 - m);
    float sum = e0 + e1;
#pragma unroll
    for (int off = 32; off > 0; off >>= 1) sum += __shfl_xor(sum, off);
    __syncthreads();
    if (ln == 0) red[wv] = sum;
    __syncthreads();
    sum = 0.f;
#pragma unroll
    for (int i = 0; i < 8; ++i) sum += red[i];
    const float inv = 1.0f / sum;
    const float a0 = e0 * inv, a1 = e1 * inv;

    float* o = out0 + (size_t)b * (TT * NN);
    unsigned short* wb = win_bf + (size_t)b * (TT * NN);
    for (int t = 0; t < TT; ++t) {
        float2 v = *(const float2*)(xb + (size_t)t * NN + tid * 2);
        float2 w; w.x = a0 * v.x; w.y = a1 * v.y;
        *(float2*)(o + (size_t)t * NN + tid * 2) = w;
        unsigned int pk = (unsigned int)f2bf(w.x) | ((unsigned int)f2bf(w.y) << 16);
        *(unsigned int*)(wb + (size_t)t * NN + tid * 2) = pk;
    }
}

// ---------------------------------------------------------------------------
// K2: convert W_ih / W_hh to bf16 with gate-interleaved row perm p=j*4+g
// ---------------------------------------------------------------------------
__global__ __launch_bounds__(256) void k_prep_w(
    const float* __restrict__ Wih, const float* __restrict__ Whh,
    const float* __restrict__ bih, const float* __restrict__ bhh,
    unsigned short* __restrict__ WihP, unsigned short* __restrict__ WhhP,
    float* __restrict__ biasP)
{
    const int p = blockIdx.x;
    const int j = p >> 2, g = p & 3;
    const int r = g * HH + j;
    const int tid = threadIdx.x;
    {
        float4 v = *(const float4*)(Wih + (size_t)r * NN + tid * 4);
        ushort4 o;
        o.x = f2bf(v.x); o.y = f2bf(v.y); o.z = f2bf(v.z); o.w = f2bf(v.w);
        *(ushort4*)(WihP + (size_t)p * NN + tid * 4) = o;
    }
    {
        float4 v = *(const float4*)(Whh + (size_t)r * HH + tid * 4);
        ushort4 o;
        o.x = f2bf(v.x); o.y = f2bf(v.y); o.z = f2bf(v.z); o.w = f2bf(v.w);
        *(ushort4*)(WhhP + (size_t)p * HH + tid * 4) = o;
    }
    if (tid == 0) biasP[p] = bih[r] + bhh[r];
}

// ---------------------------------------------------------------------------
// K3: Xp = w_in_bf16 (32768,1024) @ WihP^T (4096,1024) -> bf16 (32768,4096)
// ---------------------------------------------------------------------------
__global__ __launch_bounds__(256) void k_gemm_xp(
    const unsigned short* __restrict__ A,
    const unsigned short* __restrict__ Bm,
    unsigned short* __restrict__ C)
{
    __shared__ unsigned short lA[128 * 32];
    __shared__ unsigned short lB[128 * 32];

    const int bid = blockIdx.x;
    const int cpx = gridDim.x >> 3;
    const int swz = (bid & 7) * cpx + (bid >> 3);
    const int NTN = G4 / 128;
    const int tm = swz / NTN, tn = swz % NTN;

    const int tid = threadIdx.x;
    const int wv = tid >> 6, ln = tid & 63;
    const int wr = wv >> 1, wc = wv & 1;

    f32x4 acc[4][4] = {};

    const unsigned short* Ag = A + (size_t)tm * 128 * NN;
    const unsigned short* Bg = Bm + (size_t)tn * 128 * NN;
    const int srow = ln >> 2;
    const int sseg = ln & 3;

    for (int k0 = 0; k0 < NN; k0 += 32) {
        __syncthreads();
#pragma unroll
        for (int q = 0; q < 2; ++q) {
            const int row = wv * 32 + q * 16 + srow;
            __builtin_amdgcn_global_load_lds(
                (const __attribute__((address_space(1))) void*)(Ag + (size_t)row * NN + k0 + sseg * 8),
                (__attribute__((address_space(3))) void*)(&lA[(wv * 32 + q * 16) * 32]),
                16, 0, 0);
            __builtin_amdgcn_global_load_lds(
                (const __attribute__((address_space(1))) void*)(Bg + (size_t)row * NN + k0 + sseg * 8),
                (__attribute__((address_space(3))) void*)(&lB[(wv * 32 + q * 16) * 32]),
                16, 0, 0);
        }
        __syncthreads();

        const int rlo = ln & 15, khi = ln >> 4;
        bf16x8 af[4], bfr[4];
#pragma unroll
        for (int m = 0; m < 4; ++m)
            af[m] = *(const bf16x8*)&lA[(wr * 64 + m * 16 + rlo) * 32 + khi * 8];
#pragma unroll
        for (int n = 0; n < 4; ++n)
            bfr[n] = *(const bf16x8*)&lB[(wc * 64 + n * 16 + rlo) * 32 + khi * 8];
#pragma unroll
        for (int m = 0; m < 4; ++m)
#pragma unroll
            for (int n = 0; n < 4; ++n)
                acc[m][n] = __builtin_amdgcn_mfma_f32_16x16x32_bf16(af[m], bfr[n], acc[m][n], 0, 0, 0);
    }

    const int rlo = ln & 15, rhi = ln >> 4;
#pragma unroll
    for (int m = 0; m < 4; ++m)
#pragma unroll
        for (int n = 0; n < 4; ++n)
#pragma unroll
            for (int j = 0; j < 4; ++j) {
                const int row = tm * 128 + wr * 64 + m * 16 + rhi * 4 + j;
                const int col = tn * 128 + wc * 64 + n * 16 + rlo;
                C[(size_t)row * G4 + col] = f2bf(acc[m][n][j]);
            }
}

// ---------------------------------------------------------------------------
// K4 v3 (per step): 512 threads / 8 waves (2 waves/SIMD) to hide L2 latency.
//   64 batch x 64 perm-cols per block, 256 blocks. Wave (wr=wv>>1, wc=wv&1):
//   16-row x 32-col slice -> 1 m-frag x 2 n-frags. BK=128, 3-deep LDS
//   rotation, counted vmcnt, XOR-swizzled LDS via pre-swizzled sources.
// ---------------------------------------------------------------------------
__global__ __launch_bounds__(512) void k_step3(
    const int t,
    const unsigned short* __restrict__ hbf,
    const unsigned short* __restrict__ WhhP,
    const unsigned short* __restrict__ Xp,
    const float* __restrict__ biasP,
    float* __restrict__ cbuf,
    unsigned short* __restrict__ hbf_out,
    float* __restrict__ out1)
{
    __shared__ unsigned short lA[3][64 * 128];   // 3 x 16 KiB
    __shared__ unsigned short lB[3][64 * 128];   // 3 x 16 KiB
    __shared__ unsigned short lXp[64 * 64];      // 8 KiB

    const int bid = blockIdx.x;
    const int ti = bid >> 6, tj = bid & 63;
    const int tid = threadIdx.x;
    const int wv = tid >> 6, ln = tid & 63;      // 8 waves
    const int wr = wv >> 1, wc = wv & 1;         // wr 0..3, wc 0..1
    const int rlo = ln & 15, khi = ln >> 4;

    // ---- stage Xp tile: 1 load/thread (oldest in vmcnt queue) ----
    {
        const size_t bg = (size_t)(ti * 64 + wv * 8 + (ln >> 3));
        __builtin_amdgcn_global_load_lds(
            (const __attribute__((address_space(1))) void*)((const char*)Xp + ((bg * TT + t) << 13) + tj * 128 + (ln & 7) * 16),
            (__attribute__((address_space(3))) void*)((char*)lXp + wv * 1024),
            16, 0, 0);
    }

    const char* Ab = (const char*)hbf + (size_t)(ti * 64) * 2048;
    const char* Bb = (const char*)WhhP + (size_t)(tj * 64) * 2048;

    // 4 global_load_lds per thread per stage (2 A + 2 B); dest lane-linear.
#define STAGE(buf_, c_) do { \
    _Pragma("unroll") \
    for (int q_ = 0; q_ < 2; ++q_) { \
        const int r_ = q_ * 32 + wv * 4 + (ln >> 4); \
        const int so_ = (((ln & 15) ^ (r_ & 7)) << 4); \
        __builtin_amdgcn_global_load_lds( \
            (const __attribute__((address_space(1))) void*)(Ab + (size_t)r_ * 2048 + (c_) * 256 + so_), \
            (__attribute__((address_space(3))) void*)((char*)&lA[buf_][0] + q_ * 8192 + wv * 1024), \
            16, 0, 0); \
        __builtin_amdgcn_global_load_lds( \
            (const __attribute__((address_space(1))) void*)(Bb + (size_t)r_ * 2048 + (c_) * 256 + so_), \
            (__attribute__((address_space(3))) void*)((char*)&lB[buf_][0] + q_ * 8192 + wv * 1024), \
            16, 0, 0); \
    } } while (0)

    STAGE(0, 0);
    STAGE(1, 1);
    STAGE(2, 2);

    float4 bias4[2];
#pragma unroll
    for (int n = 0; n < 2; ++n)
        bias4[n] = *(const float4*)&biasP[(tj * 16 + wc * 8 + n * 4 + ((ln & 15) >> 2)) * 4];

    f32x4 acc[2] = {};

#pragma unroll
    for (int c = 0; c < 8; ++c) {
        const int buf = c % 3;
        if (c < 6)       { asm volatile("s_waitcnt vmcnt(8)" ::: "memory"); }
        else if (c == 6) { asm volatile("s_waitcnt vmcnt(4)" ::: "memory"); }
        else             { asm volatile("s_waitcnt vmcnt(0)" ::: "memory"); }
        __builtin_amdgcn_s_barrier();          // stage c resident

        bf16x8 af[4], bfr[4][2];
#pragma unroll
        for (int kk = 0; kk < 4; ++kk) {
            {
                const int row = wr * 16 + rlo;
                const int off = (kk * 64 + khi * 16) ^ ((row & 7) << 4);
                af[kk] = *(const bf16x8*)((const char*)&lA[buf][0] + row * 256 + off);
            }
#pragma unroll
            for (int n = 0; n < 2; ++n) {
                const int row = wc * 32 + n * 16 + rlo;
                const int off = (kk * 64 + khi * 16) ^ ((row & 7) << 4);
                bfr[kk][n] = *(const bf16x8*)((const char*)&lB[buf][0] + row * 256 + off);
            }
        }
        asm volatile("s_waitcnt lgkmcnt(0)" ::: "memory");
        __builtin_amdgcn_sched_barrier(0);
        __builtin_amdgcn_s_barrier();          // all reads of buf done
        if (c < 5) STAGE((c + 3) % 3, c + 3);  // refill this buffer
#pragma unroll
        for (int kk = 0; kk < 4; ++kk)
#pragma unroll
            for (int n = 0; n < 2; ++n)
                acc[n] = __builtin_amdgcn_mfma_f32_16x16x32_bf16(af[kk], bfr[kk][n], acc[n], 0, 0, 0);
    }
#undef STAGE

    // ---- gate transpose (verified butterfly) + LSTM pointwise ----
#pragma unroll
    for (int n = 0; n < 2; ++n) {
        f32x4 v = acc[n], u, w;
#pragma unroll
        for (int k = 0; k < 4; ++k) {
            float s = __shfl_xor(v[k ^ 1], 1);
            u[k] = ((k & 1) == (ln & 1)) ? v[k] : s;
        }
#pragma unroll
        for (int k = 0; k < 4; ++k) {
            float s = __shfl_xor(u[k ^ 2], 2);
            w[k] = (((k >> 1) & 1) == ((ln >> 1) & 1)) ? u[k] : s;
        }
        const int r_loc = wr * 16 + ((ln >> 4) << 2) + (ln & 3);
        const int u_loc = wc * 8 + n * 4 + ((ln & 15) >> 2);
        const ushort4 xp4 = *(const ushort4*)((const char*)lXp + r_loc * 128 + u_loc * 8);
        const float gi = w[0] + bf2f(xp4.x) + bias4[n].x;
        const float gf = w[1] + bf2f(xp4.y) + bias4[n].y;
        const float gg = w[2] + bf2f(xp4.z) + bias4[n].z;
        const float go = w[3] + bf2f(xp4.w) + bias4[n].w;
        const float i_ = 1.f / (1.f + expf(-gi));
        const float f_ = 1.f / (1.f + expf(-gf));
        const float g_ = tanhf(gg);
        const float o_ = 1.f / (1.f + expf(-go));
        const int bg = ti * 64 + r_loc;
        const int ug = tj * 16 + u_loc;
        const float cprev = cbuf[(size_t)bg * HH + ug];
        const float cc = f_ * cprev + i_ * g_;
        cbuf[(size_t)bg * HH + ug] = cc;
        const float h_ = o_ * tanhf(cc);
        out1[(size_t)bg * (TT * HH) + (size_t)t * HH + ug] = h_;
        hbf_out[(size_t)bg * HH + ug] = f2bf(h_);
    }
}

// zero-init: clears hbf0|hbf1|cbuf (2 MiB contiguous)
__global__ __launch_bounds__(256) void k_zero(float4* __restrict__ p)
{
    p[blockIdx.x * 256 + threadIdx.x] = make_float4(0.f, 0.f, 0.f, 0.f);
}

extern "C" void kernel_launch(void* const* d_in, const int* in_sizes, int n_in,
                              void* d_out, int out_size, void* d_ws, size_t ws_size,
                              hipStream_t stream)
{
    const float* x      = (const float*)d_in[0];
    const float* Wih    = (const float*)d_in[1];
    const float* Whh    = (const float*)d_in[2];
    const float* bih    = (const float*)d_in[3];
    const float* bhh    = (const float*)d_in[4];
    const float* attn_w = (const float*)d_in[5];
    const float* attn_b = (const float*)d_in[6];

    float* out0 = (float*)d_out;                               // (B,T,N)
    float* out1 = (float*)d_out + (size_t)BB * TT * NN;        // (B,T,H)

    char* w = (char*)d_ws;
    unsigned short* WihP  = (unsigned short*)(w);                       //  8 MiB
    unsigned short* WhhP  = (unsigned short*)(w + 8388608);             //  8 MiB
    float*          biasP = (float*)(w + 16777216);                     // 16 KiB
    unsigned short* winbf = (unsigned short*)(w + 16793600);            // 64 MiB
    unsigned short* Xp    = (unsigned short*)(w + 83902464);            // 256 MiB
    unsigned short* hbf0  = (unsigned short*)(w + 352337920);           // 512 KiB
    unsigned short* hbf1  = (unsigned short*)(w + 352862208);           // 512 KiB
    float*          cbuf  = (float*)(w + 353386496);                    //   1 MiB

    k_attn<<<BB, 512, 0, stream>>>(x, attn_w, attn_b, out0, winbf);
    k_prep_w<<<G4, 256, 0, stream>>>(Wih, Whh, bih, bhh, WihP, WhhP, biasP);
    k_gemm_xp<<<(BB * TT / 128) * (G4 / 128), 256, 0, stream>>>(winbf, WihP, Xp);
    k_zero<<<512, 256, 0, stream>>>((float4*)hbf0);   // h(t=0)=0, c=0

    for (int t = 0; t < TT; ++t) {
        const unsigned short* hin = (t & 1) ? hbf1 : hbf0;
        unsigned short* hout      = (t & 1) ? hbf0 : hbf1;
        k_step3<<<256, 512, 0, stream>>>(t, hin, WhhP, Xp, biasP, cbuf, hout, out1);
    }
}